// Round 5
// baseline (103.723 us; speedup 1.0000x reference)
//
#include <hip/hip_runtime.h>
#include <math.h>

// Sizes
#define NB 32
#define NT 1024
#define ND 128     // D_IN
#define NK 256     // D_HID
#define NO 128     // D_OUT
#define NF 513     // NT/2 + 1

#define PAD(e) ((e) + ((e) >> 4))

typedef __attribute__((ext_vector_type(8))) short bf16x8;
typedef __attribute__((ext_vector_type(4))) float f32x4;

__device__ __forceinline__ unsigned short f2bf(float f) {
  union { float f; unsigned u; } v; v.f = f;
  return (unsigned short)((v.u + 0x7fffu + ((v.u >> 16) & 1u)) >> 16);
}
__device__ __forceinline__ float bf2f(unsigned u) {
  union { unsigned u; float f; } v; v.u = u << 16;
  return v.f;
}
__device__ __forceinline__ unsigned packbf(float re, float im) {
  return (unsigned)f2bf(re) | ((unsigned)f2bf(im) << 16);
}
// base-4 digit reversal of 10-bit index
__device__ __forceinline__ unsigned digrev4(unsigned j) {
  unsigned r = __brev(j) >> 22;
  return ((r & 0x2AAu) >> 1) | ((r & 0x155u) << 1);
}

// In-place 1024-pt radix-4 FFT, one wave per FFT, SoA re/im with PAD.
template <bool INV>
__device__ void fft1024_r4(float* __restrict__ ar, float* __restrict__ ai,
                           const float* __restrict__ twc,
                           const float* __restrict__ tws, int l) {
  for (int j = l; j < 1024; j += 64) {
    int r = (int)digrev4((unsigned)j);
    if (j < r) {
      int pj = PAD(j), pr = PAD(r);
      float t0 = ar[pj], t1 = ai[pj];
      ar[pj] = ar[pr]; ai[pj] = ai[pr];
      ar[pr] = t0; ai[pr] = t1;
    }
  }
#pragma unroll
  for (int s = 0; s < 5; ++s) {
    const int sh = 2 * s;
    const int q = 1 << sh;
#pragma unroll
    for (int it = 0; it < 4; ++it) {
      int m = it * 64 + l;
      int r = m & (q - 1);
      int i0 = ((m >> sh) << (sh + 2)) + r;
      int p0 = PAD(i0), p1 = PAD(i0 + q), p2 = PAD(i0 + 2 * q), p3 = PAD(i0 + 3 * q);
      float x0r = ar[p0], x0i = ai[p0];
      float x1r = ar[p1], x1i = ai[p1];
      float x2r = ar[p2], x2i = ai[p2];
      float x3r = ar[p3], x3i = ai[p3];
      float t1r, t1i, t2r, t2i, t3r, t3i;
      if (s == 0) {
        t1r = x1r; t1i = x1i; t2r = x2r; t2i = x2i; t3r = x3r; t3i = x3i;
      } else {
        int e = r << (8 - sh);
        float c1 = twc[e], s1 = tws[e];
        float c2 = c1 * c1 - s1 * s1, s2 = 2.0f * c1 * s1;
        float c3 = c1 * c2 - s1 * s2, s3 = c1 * s2 + s1 * c2;
        t1r = x1r * c1 - x1i * s1; t1i = x1r * s1 + x1i * c1;
        t2r = x2r * c2 - x2i * s2; t2i = x2r * s2 + x2i * c2;
        t3r = x3r * c3 - x3i * s3; t3i = x3r * s3 + x3i * c3;
      }
      float u0r = x0r + t2r, u0i = x0i + t2i;
      float u1r = x0r - t2r, u1i = x0i - t2i;
      float u2r = t1r + t3r, u2i = t1i + t3i;
      float u3r = t1r - t3r, u3i = t1i - t3i;
      ar[p0] = u0r + u2r; ai[p0] = u0i + u2i;
      ar[p2] = u0r - u2r; ai[p2] = u0i - u2i;
      if (INV) {
        ar[p1] = u1r - u3i; ai[p1] = u1i + u3r;
        ar[p3] = u1r + u3i; ai[p3] = u1i - u3r;
      } else {
        ar[p1] = u1r + u3i; ai[p1] = u1i - u3r;
        ar[p3] = u1r - u3i; ai[p3] = u1i + u3r;
      }
    }
  }
}

// ---------------- forward rfft: 16 channels/block, 8 packed FFTs ----------------
__global__ __launch_bounds__(512, 4) void rfft_kernel(const float* __restrict__ x,
                                                      unsigned* __restrict__ Xc) {
  __shared__ float ar[8 * 1088], ai_[8 * 1088];  // 68 KB
  __shared__ float twc[768], tws[768];           // 6 KB
  const int tid = threadIdx.x;
  const int b = blockIdx.x >> 3;
  const int c0 = (blockIdx.x & 7) << 4;
  for (int k = tid; k < 768; k += 512) {
    float s, c;
    sincosf(6.283185307179586f * (float)k / 1024.0f, &s, &c);
    twc[k] = c; tws[k] = -s;
  }
  const float* xb = x + (size_t)b * NT * ND + c0;
  for (int idx = tid; idx < 8192; idx += 512) {
    int t = idx >> 3, g = idx & 7;
    float2 v = *(const float2*)(xb + (size_t)t * ND + 2 * g);
    int p = g * 1088 + PAD(t);
    ar[p] = v.x; ai_[p] = v.y;
  }
  __syncthreads();
  const int g = tid >> 6, l = tid & 63;
  fft1024_r4<false>(ar + g * 1088, ai_ + g * 1088, twc, tws, l);
  __syncthreads();
  // hermitian separation: ch c0+2g = even, c0+2g+1 = odd
  unsigned* Xb = Xc + (size_t)b * NF * ND + c0;
  for (int idx = tid; idx < NF * 8; idx += 512) {
    int f = idx >> 3, gg = idx & 7;
    int mr = (1024 - f) & 1023;
    int pf = gg * 1088 + PAD(f), pm = gg * 1088 + PAD(mr);
    float x1 = ar[pf], y1 = ai_[pf];
    float xr = ar[pm], yr = ai_[pm];
    unsigned e0 = packbf(0.5f * (x1 + xr), 0.5f * (y1 - yr));
    unsigned e1 = packbf(0.5f * (y1 + yr), 0.5f * (xr - x1));
    *(uint2*)(Xb + (size_t)f * ND + 2 * gg) = make_uint2(e0, e1);
  }
}

// ---------------- per-frequency complex MLP (bf16 MFMA, LDS-staged W) ----------------
// Grid NF*4: block = (f, 64-col quad). 8 waves = 2 m-halves x 4 col-groups.
// W chunk (128k x 64n, re+im) staged via float4 loads + 4x4 register transpose
// into swizzled [n][k] bf16 LDS tiles; B-fragments via ds_read_b128.
__global__ __launch_bounds__(512, 6) void freq_mfma_kernel(
    const unsigned* __restrict__ Xc, const float* __restrict__ Wre,
    const float* __restrict__ Wim, const float* __restrict__ Bre,
    const float* __restrict__ Bim, unsigned* __restrict__ Fc) {
  __shared__ unsigned short Wr_l[64 * 128], Wi_l[64 * 128];  // 32 KB
  __shared__ unsigned short Xr_l[NB * ND], Xi_l[NB * ND];    // 16 KB
  const int tid = threadIdx.x;
  const int f = blockIdx.x >> 2;
  const int n0 = (blockIdx.x & 3) << 6;

  // ---- stage W: thread owns a 4x4 tile (rows 4g..4g+3, local cols 4cq..4cq+3)
  {
    const int g = tid >> 4;
    const int cq = tid & 15;
    const float* w0 = Wre + (size_t)f * ND * NK + n0 + cq * 4;
    const float* w1 = Wim + (size_t)f * ND * NK + n0 + cq * 4;
#pragma unroll
    for (int w = 0; w < 2; ++w) {
      const float* wb = w ? w1 : w0;
      unsigned short* wl = w ? Wi_l : Wr_l;
      float4 r0 = *(const float4*)(wb + (size_t)(4 * g + 0) * NK);
      float4 r1 = *(const float4*)(wb + (size_t)(4 * g + 1) * NK);
      float4 r2 = *(const float4*)(wb + (size_t)(4 * g + 2) * NK);
      float4 r3 = *(const float4*)(wb + (size_t)(4 * g + 3) * NK);
      const float* c0 = (const float*)&r0;
      const float* c1 = (const float*)&r1;
      const float* c2 = (const float*)&r2;
      const float* c3 = (const float*)&r3;
#pragma unroll
      for (int j = 0; j < 4; ++j) {
        int nl = cq * 4 + j;
        int sw = (nl >> 2) ^ ((nl & 3) << 2);
        int off = nl * 128 + (((g >> 1) ^ sw) << 3) + ((g & 1) << 2);
        ushort4 v;
        v.x = f2bf(c0[j]); v.y = f2bf(c1[j]);
        v.z = f2bf(c2[j]); v.w = f2bf(c3[j]);
        *(ushort4*)&wl[off] = v;
      }
    }
  }
  // ---- stage X: uint2 (2 channels) per task, split packed re/im
#pragma unroll
  for (int it = 0; it < 4; ++it) {
    int idx = it * 512 + tid;
    int bb = idx >> 6, dp = idx & 63;
    int d = dp * 2;
    uint2 u = *(const uint2*)(Xc + ((size_t)bb * NF + f) * ND + d);
    unsigned re2 = (u.x & 0xffffu) | (u.y << 16);
    unsigned im2 = (u.x >> 16) | (u.y & 0xffff0000u);
    int off = bb * 128 + ((((d >> 3) ^ (bb & 15))) << 3) + (d & 7);
    *(unsigned*)&Xr_l[off] = re2;
    *(unsigned*)&Xi_l[off] = im2;
  }
  __syncthreads();

  const int wv = tid >> 6, l = tid & 63;
  const int lr = l & 15, lg = l >> 4;
  const int wvn = wv & 3, mh = wv >> 2;
  const int nl = wvn * 16 + lr;
  const int swn = (nl >> 2) ^ ((nl & 3) << 2);
  const int row = mh * 16 + lr;
  f32x4 aR, aI;
  {
    float br = Bre[(size_t)f * NK + n0 + nl];
    float bi = Bim[(size_t)f * NK + n0 + nl];
    aR = (f32x4){br, br, br, br};
    aI = (f32x4){bi, bi, bi, bi};
  }
#pragma unroll
  for (int ks = 0; ks < 4; ++ks) {
    int kb = ks * 4 + lg;
    bf16x8 xr = *(const bf16x8*)&Xr_l[row * 128 + ((kb ^ lr) << 3)];
    bf16x8 xi = *(const bf16x8*)&Xi_l[row * 128 + ((kb ^ lr) << 3)];
    bf16x8 bR = *(const bf16x8*)&Wr_l[nl * 128 + ((kb ^ swn) << 3)];
    bf16x8 bI = *(const bf16x8*)&Wi_l[nl * 128 + ((kb ^ swn) << 3)];
    union { bf16x8 v; unsigned u[4]; } xiu, xnu;
    xiu.v = xi;
    xnu.u[0] = xiu.u[0] ^ 0x80008000u;
    xnu.u[1] = xiu.u[1] ^ 0x80008000u;
    xnu.u[2] = xiu.u[2] ^ 0x80008000u;
    xnu.u[3] = xiu.u[3] ^ 0x80008000u;
    aR = __builtin_amdgcn_mfma_f32_16x16x32_bf16(xr, bR, aR, 0, 0, 0);
    aR = __builtin_amdgcn_mfma_f32_16x16x32_bf16(xnu.v, bI, aR, 0, 0, 0);
    aI = __builtin_amdgcn_mfma_f32_16x16x32_bf16(xr, bI, aI, 0, 0, 0);
    aI = __builtin_amdgcn_mfma_f32_16x16x32_bf16(xi, bR, aI, 0, 0, 0);
  }
#pragma unroll
  for (int r = 0; r < 4; ++r) {
    int brow = mh * 16 + lg * 4 + r;
    float vR = fmaxf(aR[r], 0.0f);
    float vI = fmaxf(aI[r], 0.0f);
    Fc[((size_t)brow * NF + f) * NK + n0 + nl] = packbf(vR, vI);
  }
}

// ---------------- inverse rfft: 16 channels/block, 8 packed inverse FFTs ----------------
__global__ __launch_bounds__(512, 4) void irfft_kernel(const unsigned* __restrict__ Fc,
                                                       unsigned short* __restrict__ yf) {
  __shared__ float ar[8 * 1088], ai_[8 * 1088];
  __shared__ float twc[768], tws[768];
  const int tid = threadIdx.x;
  const int b = blockIdx.x >> 4;
  const int k0 = (blockIdx.x & 15) << 4;
  for (int k = tid; k < 768; k += 512) {
    float s, c;
    sincosf(6.283185307179586f * (float)k / 1024.0f, &s, &c);
    twc[k] = c; tws[k] = s;   // inverse: conjugated twiddles
  }
  // build Z[f] = Fa[f] + i*Fb[f] with hermitian extension
  for (int idx = tid; idx < 8192; idx += 512) {
    int f = idx >> 3, g = idx & 7;
    int src = (f <= 512) ? f : 1024 - f;
    uint2 u = *(const uint2*)(Fc + ((size_t)b * NF + src) * NK + k0 + 2 * g);
    float arr = bf2f(u.x & 0xffff), ari = bf2f(u.x >> 16);
    float brr = bf2f(u.y & 0xffff), bri = bf2f(u.y >> 16);
    float zr, zi;
    if (f <= 512) { zr = arr - bri; zi = ari + brr; }
    else          { zr = arr + bri; zi = brr - ari; }
    int p = g * 1088 + PAD(f);
    ar[p] = zr; ai_[p] = zi;
  }
  __syncthreads();
  const int g = tid >> 6, l = tid & 63;
  fft1024_r4<true>(ar + g * 1088, ai_ + g * 1088, twc, tws, l);
  __syncthreads();
  const float sc = 1.0f / 1024.0f;
  unsigned* yb = (unsigned*)(yf + (size_t)b * NT * NK + k0);
  for (int idx = tid; idx < 8192; idx += 512) {
    int t = idx >> 3, gg = idx & 7;
    int p = gg * 1088 + PAD(t);
    yb[(size_t)t * (NK / 2) + gg] = packbf(ar[p] * sc, ai_[p] * sc);
  }
}

// ---------------- weight convert + transpose to bf16 ----------------
// Wt: [0:32768) Wrc_t[256][128]; [32768:98304) W1_t[256][256]; [98304:131072) W2_t[128][256]
__global__ __launch_bounds__(256) void wconv_kernel(const float* __restrict__ Wrc,
                                                    const float* __restrict__ W1,
                                                    const float* __restrict__ W2,
                                                    unsigned short* __restrict__ Wt) {
  int i = blockIdx.x * 256 + threadIdx.x;
  if (i < 32768) {
    int k = i >> 8, n = i & 255;
    Wt[n * 128 + k] = f2bf(Wrc[i]);
  } else if (i < 98304) {
    int j = i - 32768; int k = j >> 8, n = j & 255;
    Wt[32768 + n * 256 + k] = f2bf(W1[j]);
  } else if (i < 131072) {
    int j = i - 98304; int k = j >> 7, n = j & 127;
    Wt[98304 + n * 256 + k] = f2bf(W2[j]);
  }
}

// ---------------- fused MLP tail ----------------
// Block = 64 rows. Wave = 64 rows x 32 cols (GEMM1/2), 64 x 16 (GEMM3).
__global__ __launch_bounds__(512, 4) void mlp_fused_kernel(
    const float* __restrict__ x, const unsigned short* __restrict__ yf,
    const unsigned short* __restrict__ Wt, const float* __restrict__ b1,
    const float* __restrict__ b2, float* __restrict__ out) {
  __shared__ unsigned short y_l[64 * 256];  // 32 KB
  __shared__ unsigned short u_l[64 * 256];  // 32 KB: x-tile (bf16), then h
  const int tid = threadIdx.x;
  const int wv = tid >> 6, l = tid & 63;
  const int lr = l & 15, lg = l >> 4;
  const int row0 = blockIdx.x * 64;
  const unsigned short* W1_t = Wt + 32768;
  const unsigned short* W2_t = Wt + 98304;

  // stage x -> u_l [64][128] bf16, 16B-block swizzle
#pragma unroll
  for (int it = 0; it < 4; ++it) {
    int idx = it * 512 + tid;
    int row = idx >> 5, c4 = idx & 31;
    float4 v = *(const float4*)(x + (size_t)(row0 + row) * ND + c4 * 4);
    int blk = (c4 >> 1) ^ (row & 15);
    unsigned short* p = &u_l[row * 128 + blk * 8 + (c4 & 1) * 4];
    p[0] = f2bf(v.x); p[1] = f2bf(v.y); p[2] = f2bf(v.z); p[3] = f2bf(v.w);
  }
  __syncthreads();

  // ---- GEMM1: P = x @ W_rc (K=128) ----
  f32x4 acc[4][2];
#pragma unroll
  for (int m = 0; m < 4; ++m)
#pragma unroll
    for (int nt = 0; nt < 2; ++nt) acc[m][nt] = (f32x4){0.f, 0.f, 0.f, 0.f};
#pragma unroll
  for (int ks = 0; ks < 4; ++ks) {
    bf16x8 bb[2];
#pragma unroll
    for (int nt = 0; nt < 2; ++nt) {
      int col = wv * 32 + nt * 16 + lr;
      bb[nt] = *(const bf16x8*)&Wt[col * 128 + ks * 32 + lg * 8];
    }
    bf16x8 aa[4];
#pragma unroll
    for (int m = 0; m < 4; ++m) {
      int row = m * 16 + lr;
      aa[m] = *(const bf16x8*)&u_l[row * 128 + (((ks * 4 + lg) ^ (row & 15)) << 3)];
    }
#pragma unroll
    for (int m = 0; m < 4; ++m)
#pragma unroll
      for (int nt = 0; nt < 2; ++nt)
        acc[m][nt] = __builtin_amdgcn_mfma_f32_16x16x32_bf16(aa[m], bb[nt], acc[m][nt], 0, 0, 0);
  }
  // epilogue: y = P + yf -> y_l (swizzled bf16)
#pragma unroll
  for (int m = 0; m < 4; ++m)
#pragma unroll
    for (int nt = 0; nt < 2; ++nt)
#pragma unroll
      for (int r = 0; r < 4; ++r) {
        int row = m * 16 + lg * 4 + r;
        int col = wv * 32 + nt * 16 + lr;
        float v = acc[m][nt][r] + bf2f(yf[(size_t)(row0 + row) * NK + col]);
        int blk = (col >> 3) ^ (row & 31);
        y_l[row * 256 + blk * 8 + (col & 7)] = f2bf(v);
      }
  __syncthreads();

  // ---- GEMM2: h = leaky(y @ W1 + b1) (K=256) ----
  f32x4 a2[4][2];
  {
    float bv0 = b1[wv * 32 + lr], bv1 = b1[wv * 32 + 16 + lr];
#pragma unroll
    for (int m = 0; m < 4; ++m) {
      a2[m][0] = (f32x4){bv0, bv0, bv0, bv0};
      a2[m][1] = (f32x4){bv1, bv1, bv1, bv1};
    }
  }
#pragma unroll
  for (int ks = 0; ks < 8; ++ks) {
    bf16x8 bb[2];
#pragma unroll
    for (int nt = 0; nt < 2; ++nt) {
      int col = wv * 32 + nt * 16 + lr;
      bb[nt] = *(const bf16x8*)&W1_t[col * 256 + ks * 32 + lg * 8];
    }
    bf16x8 aa[4];
#pragma unroll
    for (int m = 0; m < 4; ++m) {
      int row = m * 16 + lr;
      aa[m] = *(const bf16x8*)&y_l[row * 256 + (((ks * 4 + lg) ^ (row & 31)) << 3)];
    }
#pragma unroll
    for (int m = 0; m < 4; ++m)
#pragma unroll
      for (int nt = 0; nt < 2; ++nt)
        a2[m][nt] = __builtin_amdgcn_mfma_f32_16x16x32_bf16(aa[m], bb[nt], a2[m][nt], 0, 0, 0);
  }
#pragma unroll
  for (int m = 0; m < 4; ++m)
#pragma unroll
    for (int nt = 0; nt < 2; ++nt)
#pragma unroll
      for (int r = 0; r < 4; ++r) {
        int row = m * 16 + lg * 4 + r;
        int col = wv * 32 + nt * 16 + lr;
        float v = a2[m][nt][r];
        v = (v > 0.0f) ? v : 0.01f * v;
        int blk = (col >> 3) ^ (row & 31);
        u_l[row * 256 + blk * 8 + (col & 7)] = f2bf(v);
      }
  __syncthreads();

  // ---- GEMM3: out = h @ W2 + b2 (K=256, N=128) ----
  const int col3 = wv * 16 + lr;
  f32x4 a3[4];
  {
    float bv = b2[col3];
#pragma unroll
    for (int m = 0; m < 4; ++m) a3[m] = (f32x4){bv, bv, bv, bv};
  }
#pragma unroll
  for (int ks = 0; ks < 8; ++ks) {
    bf16x8 bb = *(const bf16x8*)&W2_t[col3 * 256 + ks * 32 + lg * 8];
    bf16x8 aa[4];
#pragma unroll
    for (int m = 0; m < 4; ++m) {
      int row = m * 16 + lr;
      aa[m] = *(const bf16x8*)&u_l[row * 256 + (((ks * 4 + lg) ^ (row & 31)) << 3)];
    }
#pragma unroll
    for (int m = 0; m < 4; ++m)
      a3[m] = __builtin_amdgcn_mfma_f32_16x16x32_bf16(aa[m], bb, a3[m], 0, 0, 0);
  }
#pragma unroll
  for (int m = 0; m < 4; ++m)
#pragma unroll
    for (int r = 0; r < 4; ++r) {
      int row = m * 16 + lg * 4 + r;
      out[(size_t)(row0 + row) * NO + col3] = a3[m][r];
    }
}

extern "C" void kernel_launch(void* const* d_in, const int* in_sizes, int n_in,
                              void* d_out, int out_size, void* d_ws, size_t ws_size,
                              hipStream_t stream) {
  const float* x     = (const float*)d_in[0];
  const float* W_re  = (const float*)d_in[1];
  const float* W_im  = (const float*)d_in[2];
  const float* B_re  = (const float*)d_in[3];
  const float* B_im  = (const float*)d_in[4];
  const float* W_rc  = (const float*)d_in[5];
  const float* fc1_w = (const float*)d_in[6];
  const float* fc1_b = (const float*)d_in[7];
  const float* fc2_w = (const float*)d_in[8];
  const float* fc2_b = (const float*)d_in[9];
  float* out = (float*)d_out;

  // Workspace: Xc 8.4MB | Fc 16.8MB | yf 16.8MB | Wt 0.26MB
  const size_t SZ_X = (size_t)NB * NF * ND;  // 2,101,248
  const size_t SZ_F = (size_t)NB * NF * NK;  // 4,202,496
  const size_t SZ_Y = (size_t)NB * NT * NK;  // 8,388,608
  unsigned* Xc = (unsigned*)d_ws;
  unsigned* Fc = Xc + SZ_X;
  unsigned short* yf = (unsigned short*)(Fc + SZ_F);
  unsigned short* Wt = yf + SZ_Y;

  wconv_kernel<<<dim3(512), dim3(256), 0, stream>>>(W_rc, fc1_w, fc2_w, Wt);
  rfft_kernel<<<dim3(NB * 8), dim3(512), 0, stream>>>(x, Xc);
  freq_mfma_kernel<<<dim3(NF * 4), dim3(512), 0, stream>>>(Xc, W_re, W_im, B_re, B_im, Fc);
  irfft_kernel<<<dim3(NB * 16), dim3(512), 0, stream>>>(Fc, yf);
  mlp_fused_kernel<<<dim3((NB * NT) / 64), dim3(512), 0, stream>>>(x, yf, Wt, fc1_b, fc2_b, out);
}